// Round 1
// baseline (60.181 us; speedup 1.0000x reference)
//
#include <hip/hip_runtime.h>
#include <hip/hip_bf16.h>

// Decorrelation forward:
// out[n,j] = x[n,j] + sum_{i<j} sum_k Bin(9,k)*u_i^k*(1-u_i)^(9-k) * P[k,(i,j)] * x[n,i]
// u_i = (x[n,i] - lo_i) / (hi_i - lo_i)
//
// Weights are repacked by a prep kernel into d_ws:
//   W[0..1199]   : binom(9,k)*params[k, pairIdx] in (i asc, j asc, k asc) traversal order
//   W[1200..1215]: lo[i]
//   W[1216..1231]: 1/(hi[i]-lo[i])

#define DVARS 16
#define KB 10          // degree 9 -> 10 basis funcs
#define NPAIRS 120
#define NW (NPAIRS * KB)   // 1200

__global__ void decorr_prep(const float* __restrict__ params,
                            const float* __restrict__ poly_range,
                            float* __restrict__ W) {
    int t = blockIdx.x * blockDim.x + threadIdx.x;
    if (t < NW) {
        int k = t % KB;
        int pairIdx = t / KB;     // enumerates (i, j) with i ascending, j in (i, 16)
        int i = 0, rem = pairIdx;
        while (rem >= (DVARS - 1) - i) { rem -= (DVARS - 1) - i; ++i; }
        int j = i + 1 + rem;
        int pidx = j * (j - 1) / 2 + i;     // reference PAIRS order: by var j, then covar i
        const float BIN[KB] = {1.f, 9.f, 36.f, 84.f, 126.f, 126.f, 84.f, 36.f, 9.f, 1.f};
        W[t] = BIN[k] * params[k * NPAIRS + pidx];
    }
    if (t < DVARS) {
        float lo = poly_range[t];
        float hi = poly_range[DVARS + t];
        W[NW + t] = lo;
        W[NW + DVARS + t] = 1.0f / (hi - lo);
    }
}

__global__ __launch_bounds__(256) void decorr_main(const float* __restrict__ x,
                                                   const float* __restrict__ W,
                                                   float* __restrict__ out,
                                                   int nSamples) {
    int n = blockIdx.x * 256 + threadIdx.x;
    if (n >= nSamples) return;

    const float4* xr = reinterpret_cast<const float4*>(x + (size_t)n * DVARS);
    float4 a0 = xr[0], a1 = xr[1], a2 = xr[2], a3 = xr[3];
    float xv[DVARS] = {a0.x, a0.y, a0.z, a0.w,
                       a1.x, a1.y, a1.z, a1.w,
                       a2.x, a2.y, a2.z, a2.w,
                       a3.x, a3.y, a3.z, a3.w};

    float acc[DVARS];
#pragma unroll
    for (int j = 0; j < DVARS; ++j) acc[j] = xv[j];

    const float* __restrict__ Lo  = W + NW;
    const float* __restrict__ Inv = W + NW + DVARS;

    int pos = 0;
#pragma unroll
    for (int i = 0; i < DVARS - 1; ++i) {
        float u = (xv[i] - Lo[i]) * Inv[i];
        float v = 1.0f - u;
        float up[KB], vp[KB];
        up[0] = 1.0f; vp[0] = 1.0f;
#pragma unroll
        for (int k = 1; k < KB; ++k) { up[k] = up[k - 1] * u; vp[k] = vp[k - 1] * v; }
        float t[KB];
#pragma unroll
        for (int k = 0; k < KB; ++k) t[k] = up[k] * vp[KB - 1 - k] * xv[i];
#pragma unroll
        for (int j = i + 1; j < DVARS; ++j) {
#pragma unroll
            for (int k = 0; k < KB; ++k) {
                acc[j] = fmaf(t[k], W[pos + k], acc[j]);
            }
            pos += KB;
        }
    }

    float4* orow = reinterpret_cast<float4*>(out + (size_t)n * DVARS);
    orow[0] = make_float4(acc[0],  acc[1],  acc[2],  acc[3]);
    orow[1] = make_float4(acc[4],  acc[5],  acc[6],  acc[7]);
    orow[2] = make_float4(acc[8],  acc[9],  acc[10], acc[11]);
    orow[3] = make_float4(acc[12], acc[13], acc[14], acc[15]);
}

extern "C" void kernel_launch(void* const* d_in, const int* in_sizes, int n_in,
                              void* d_out, int out_size, void* d_ws, size_t ws_size,
                              hipStream_t stream) {
    const float* x      = (const float*)d_in[0];   // [N, 16]
    const float* params = (const float*)d_in[1];   // [10, 120]
    const float* prange = (const float*)d_in[2];   // [2, 16]
    float* out = (float*)d_out;
    float* W   = (float*)d_ws;                     // needs 1232 floats = 4928 B

    int nSamples = in_sizes[0] / DVARS;

    decorr_prep<<<(NW + 255) / 256, 256, 0, stream>>>(params, prange, W);
    decorr_main<<<(nSamples + 255) / 256, 256, 0, stream>>>(x, W, out, nSamples);
}